// Round 2
// baseline (690.490 us; speedup 1.0000x reference)
//
#include <hip/hip_runtime.h>

#define NWIN 1024
#define LTOK 256
#define EMB  192
#define NPAT 64
#define NHEAD 6
#define HDIM 32
#define SCALE 0.08838834764831845f
#define LN_EPS 1e-5f

typedef float f32x4 __attribute__((ext_vector_type(4)));
typedef short s16x8 __attribute__((ext_vector_type(8)));

// ---- attention kernel LDS layout (bytes) ----
#define OFF_KH  0              // [64 p][128 sc] bf16, row 256B, swz ((p&7)<<4)
#define OFF_VT  16384          // [128 sc][64 p] bf16, row 128B, swz ((sc&7)<<4)
#define OFF_PB  32768          // [64 q][64 k]  bf16, row 128B, swz ((q&7)<<4)
#define OFF_SB  40960          // 64 rows x 272B f32 (68 dwords) ; reused: phase1 partials, PV out stage [64 qp][128 sc] bf16 row 256B
#define OFF_ST  58368          // stats: 6 x 64 f32
#define OFF_BH  59904          // bias_h: 225 f32 (pad 1024B)
#define SMEM_BYTES 60928

__device__ __forceinline__ unsigned short f2bf(float f) {
    unsigned u = __float_as_uint(f);
    u += 0x7fffu + ((u >> 16) & 1u);
    return (unsigned short)(u >> 16);
}

__device__ __forceinline__ int tok_of(int p, int s) {
    // t = wh*32 + sh*16 + ww*2 + sw ; p = wh*8+ww, s = sh*2+sw
    return ((p >> 3) << 5) + ((s >> 1) << 4) + ((p & 7) << 1) + (s & 1);
}

__device__ __forceinline__ f32x4 mfma16(s16x8 a, s16x8 b, f32x4 c) {
    return __builtin_amdgcn_mfma_f32_16x16x32_bf16(a, b, c, 0, 0, 0);
}

__device__ __forceinline__ s16x8 ln_pack8(const float* __restrict__ x,
                                          float mu, float rs,
                                          const float* __restrict__ wl,
                                          const float* __restrict__ bl,
                                          float scale) {
    f32x4 a  = *(const f32x4*)x;
    f32x4 b  = *(const f32x4*)(x + 4);
    f32x4 w0 = *(const f32x4*)wl;
    f32x4 w1 = *(const f32x4*)(wl + 4);
    f32x4 c0 = *(const f32x4*)bl;
    f32x4 c1 = *(const f32x4*)(bl + 4);
    s16x8 r;
    r[0] = (short)f2bf(((a[0]-mu)*rs*w0[0] + c0[0])*scale);
    r[1] = (short)f2bf(((a[1]-mu)*rs*w0[1] + c0[1])*scale);
    r[2] = (short)f2bf(((a[2]-mu)*rs*w0[2] + c0[2])*scale);
    r[3] = (short)f2bf(((a[3]-mu)*rs*w0[3] + c0[3])*scale);
    r[4] = (short)f2bf(((b[0]-mu)*rs*w1[0] + c1[0])*scale);
    r[5] = (short)f2bf(((b[1]-mu)*rs*w1[1] + c1[1])*scale);
    r[6] = (short)f2bf(((b[2]-mu)*rs*w1[2] + c1[2])*scale);
    r[7] = (short)f2bf(((b[3]-mu)*rs*w1[3] + c1[3])*scale);
    return r;
}

__device__ __forceinline__ void ln_f8(const float* __restrict__ x,
                                      float mu, float rs,
                                      const float* __restrict__ wl,
                                      const float* __restrict__ bl,
                                      float* o) {
    f32x4 a  = *(const f32x4*)x;
    f32x4 b  = *(const f32x4*)(x + 4);
    f32x4 w0 = *(const f32x4*)wl;
    f32x4 w1 = *(const f32x4*)(wl + 4);
    f32x4 c0 = *(const f32x4*)bl;
    f32x4 c1 = *(const f32x4*)(bl + 4);
    o[0] = (a[0]-mu)*rs*w0[0] + c0[0];
    o[1] = (a[1]-mu)*rs*w0[1] + c0[1];
    o[2] = (a[2]-mu)*rs*w0[2] + c0[2];
    o[3] = (a[3]-mu)*rs*w0[3] + c0[3];
    o[4] = (b[0]-mu)*rs*w1[0] + c1[0];
    o[5] = (b[1]-mu)*rs*w1[1] + c1[1];
    o[6] = (b[2]-mu)*rs*w1[2] + c1[2];
    o[7] = (b[3]-mu)*rs*w1[3] + c1[3];
}

// Pre-projection bf16 rows live INSIDE d_out: window w, token t occupies
// bytes [w*196608 + t*768 + 384, +384) (i.e. the second half of each output
// row). The projection kernel reads a strip's pre rows into registers before
// any store to that strip (data dependence), so the in-place overwrite is safe.

__global__ __launch_bounds__(512, 4) void dwa_attn_kernel(
    const float* __restrict__ q_g, const float* __restrict__ k_g,
    const float* __restrict__ v_g, const float* __restrict__ mask_g,
    const float* __restrict__ lnqw, const float* __restrict__ lnqb,
    const float* __restrict__ lnkw, const float* __restrict__ lnkb,
    const float* __restrict__ lnvw, const float* __restrict__ lnvb,
    const float* __restrict__ btab, float* __restrict__ out_g)
{
    __shared__ __align__(16) char smem[SMEM_BYTES];

    const int tid  = threadIdx.x;
    const int lane = tid & 63;
    const int wv   = tid >> 6;
    const int win  = blockIdx.x;
    const size_t wbase = (size_t)win * LTOK * EMB;
    char* preb = (char*)out_g + (size_t)win * 196608;

    float* stats = (float*)(smem + OFF_ST);
    float* muq = stats;       float* rsq = stats + 64;
    float* muk = stats + 128; float* rsk = stats + 192;
    float* muv = stats + 256; float* rsv = stats + 320;
    float* biash = (float*)(smem + OFF_BH);

    // ---------------- Phase 1: LN stats for q,k,v (single pass) ----------------
    {
        float* part = (float*)(smem + OFF_SB);   // [256 t][2 half][6]
        const int t = tid >> 1, half = tid & 1;
        const f32x4* qp = (const f32x4*)(q_g + wbase + t*EMB + half*96);
        const f32x4* kp = (const f32x4*)(k_g + wbase + t*EMB + half*96);
        const f32x4* vp = (const f32x4*)(v_g + wbase + t*EMB + half*96);
        float s1q=0.f,s2q=0.f,s1k=0.f,s2k=0.f,s1v=0.f,s2v=0.f;
        #pragma unroll 4
        for (int i = 0; i < 24; ++i) {
            f32x4 a = qp[i];
            s1q += a[0]+a[1]+a[2]+a[3];
            s2q += a[0]*a[0]+a[1]*a[1]+a[2]*a[2]+a[3]*a[3];
            f32x4 b = kp[i];
            s1k += b[0]+b[1]+b[2]+b[3];
            s2k += b[0]*b[0]+b[1]*b[1]+b[2]*b[2]+b[3]*b[3];
            f32x4 c = vp[i];
            s1v += c[0]+c[1]+c[2]+c[3];
            s2v += c[0]*c[0]+c[1]*c[1]+c[2]*c[2]+c[3]*c[3];
        }
        float* pp = part + (t*2 + half)*6;
        pp[0]=s1q; pp[1]=s2q; pp[2]=s1k; pp[3]=s2k; pp[4]=s1v; pp[5]=s2v;
        __syncthreads();
        if (tid < NPAT) {
            float S[6] = {0.f,0.f,0.f,0.f,0.f,0.f};
            #pragma unroll
            for (int s = 0; s < 4; ++s) {
                int tt = tok_of(tid, s);
                const float* pr = part + tt*12;
                #pragma unroll
                for (int x = 0; x < 6; ++x) S[x] += pr[x] + pr[6 + x];
            }
            #pragma unroll
            for (int x = 0; x < 3; ++x) {
                float mu  = S[2*x] * (1.f/768.f);
                float var = S[2*x+1] * (1.f/768.f) - mu*mu;
                stats[x*128 + tid]      = mu;
                stats[x*128 + 64 + tid] = rsqrtf(var + LN_EPS);
            }
        }
        __syncthreads();
    }

    const int mwin = win & 63;
    const float* mask_w = mask_g + (size_t)mwin * NPAT * NPAT;

    // ---------------- Phase 2: per-head attention ----------------
    for (int h = 0; h < NHEAD; ++h) {
        // ---- stage Kh (row-major) + Vt (transposed), normalized bf16 ----
        if (tid < 225) biash[tid] = btab[tid * NHEAD + h];
        {
            const int p = tid & 63;              // lane-distinct patch: bank-friendly
            #pragma unroll
            for (int i = 0; i < 2; ++i) {
                int scb = (tid >> 6) * 2 + i;    // 0..15
                int s   = scb >> 2;
                int co  = (scb & 3) * 8;
                int t   = tok_of(p, s);
                int chb = h * HDIM + co;
                // K
                {
                    const float* kp = k_g + wbase + t*EMB + chb;
                    s16x8 kk = ln_pack8(kp, muk[p], rsk[p],
                                        lnkw + s*EMB + chb, lnkb + s*EMB + chb, 1.0f);
                    *(s16x8*)(smem + OFF_KH + p*256 + ((scb*16) ^ ((p & 7) << 4))) = kk;
                }
                // V (scatter into transposed layout; p=lane -> 2-way banks)
                {
                    const float* vp = v_g + wbase + t*EMB + chb;
                    float vn[8];
                    ln_f8(vp, muv[p], rsv[p], lnvw + s*EMB + chb, lnvb + s*EMB + chb, vn);
                    #pragma unroll
                    for (int j = 0; j < 8; ++j) {
                        int sc = scb*8 + j;
                        *(unsigned short*)(smem + OFF_VT + sc*128 + ((p*2) ^ ((sc & 7) << 4)))
                            = f2bf(vn[j]);
                    }
                }
            }
        }
        __syncthreads();   // sync1

        // ---- QK^T : wave = (mstrip, nhalf) ----
        {
            int mstrip = wv >> 1, nhalf = wv & 1;
            int pr = mstrip*16 + (lane & 15);
            int cb = lane >> 4;
            float mu = muq[pr], rs = rsq[pr];
            f32x4 acc0 = {0.f,0.f,0.f,0.f};
            f32x4 acc1 = {0.f,0.f,0.f,0.f};
            #pragma unroll
            for (int ks = 0; ks < 4; ++ks) {
                int s = ks;
                int t = tok_of(pr, s);
                int chb = h*HDIM + cb*8;
                s16x8 af = ln_pack8(q_g + wbase + t*EMB + chb, mu, rs,
                                    lnqw + s*EMB + chb, lnqb + s*EMB + chb, SCALE);
                {
                    int row = (nhalf*2 + 0)*16 + (lane & 15);
                    s16x8 bf = *(const s16x8*)(smem + OFF_KH + row*256 +
                                  ((ks*64 + cb*16) ^ ((row & 7) << 4)));
                    acc0 = mfma16(af, bf, acc0);
                }
                {
                    int row = (nhalf*2 + 1)*16 + (lane & 15);
                    s16x8 bf = *(const s16x8*)(smem + OFF_KH + row*256 +
                                  ((ks*64 + cb*16) ^ ((row & 7) << 4)));
                    acc1 = mfma16(af, bf, acc1);
                }
            }
            float* Sb = (float*)(smem + OFF_SB);
            #pragma unroll
            for (int r = 0; r < 4; ++r) {
                int qr = mstrip*16 + (lane >> 4)*4 + r;
                Sb[qr*68 + (nhalf*2+0)*16 + (lane & 15)] = acc0[r];
                Sb[qr*68 + (nhalf*2+1)*16 + (lane & 15)] = acc1[r];
            }
        }
        __syncthreads();   // sync2

        // ---- softmax (+bias +mask) : 8 threads per row ----
        {
            int qr = tid >> 3, j = tid & 7;
            const float* Sb = (const float*)(smem + OFF_SB);
            f32x4 s0 = *(const f32x4*)(Sb + qr*68 + j*8);
            f32x4 s1 = *(const f32x4*)(Sb + qr*68 + j*8 + 4);
            f32x4 m0 = *(const f32x4*)(mask_w + qr*64 + j*8);
            f32x4 m1 = *(const f32x4*)(mask_w + qr*64 + j*8 + 4);
            int qh = qr >> 3, qw = qr & 7;
            float vals[8];
            #pragma unroll
            for (int jj = 0; jj < 8; ++jj) {
                int kc = j*8 + jj;
                int idx = (qh - (kc >> 3) + 7)*15 + (qw - (kc & 7) + 7);
                float sv = (jj < 4 ? s0[jj] : s1[jj-4]) +
                           (jj < 4 ? m0[jj] : m1[jj-4]) + biash[idx];
                vals[jj] = sv;
            }
            float mx = vals[0];
            #pragma unroll
            for (int jj = 1; jj < 8; ++jj) mx = fmaxf(mx, vals[jj]);
            mx = fmaxf(mx, __shfl_xor(mx, 1));
            mx = fmaxf(mx, __shfl_xor(mx, 2));
            mx = fmaxf(mx, __shfl_xor(mx, 4));
            float sum = 0.f;
            #pragma unroll
            for (int jj = 0; jj < 8; ++jj) { vals[jj] = __expf(vals[jj] - mx); sum += vals[jj]; }
            sum += __shfl_xor(sum, 1);
            sum += __shfl_xor(sum, 2);
            sum += __shfl_xor(sum, 4);
            float rinv = 1.f / sum;
            s16x8 pv;
            #pragma unroll
            for (int jj = 0; jj < 8; ++jj) pv[jj] = (short)f2bf(vals[jj] * rinv);
            *(s16x8*)(smem + OFF_PB + qr*128 + ((j*16) ^ ((qr & 7) << 4))) = pv;
        }
        __syncthreads();   // sync3

        // ---- P @ V : wave = (m, nset); scatter PV out into SB region (bf16) ----
        {
            int m = wv >> 1, nset = wv & 1;
            int cb = lane >> 4;
            int prow = m*16 + (lane & 15);
            s16x8 ap0 = *(const s16x8*)(smem + OFF_PB + prow*128 +
                          ((0*64 + cb*16) ^ ((prow & 7) << 4)));
            s16x8 ap1 = *(const s16x8*)(smem + OFF_PB + prow*128 +
                          ((1*64 + cb*16) ^ ((prow & 7) << 4)));
            #pragma unroll
            for (int i = 0; i < 4; ++i) {
                int nt = nset*4 + i;
                int brow = nt*16 + (lane & 15);     // sc
                f32x4 acc = {0.f,0.f,0.f,0.f};
                s16x8 bf0 = *(const s16x8*)(smem + OFF_VT + brow*128 +
                              ((0*64 + cb*16) ^ ((brow & 7) << 4)));
                s16x8 bf1 = *(const s16x8*)(smem + OFF_VT + brow*128 +
                              ((1*64 + cb*16) ^ ((brow & 7) << 4)));
                acc = mfma16(ap0, bf0, acc);
                acc = mfma16(ap1, bf1, acc);
                int sc = nt*16 + (lane & 15);
                #pragma unroll
                for (int r = 0; r < 4; ++r) {
                    int qp = m*16 + (lane >> 4)*4 + r;
                    *(unsigned short*)(smem + OFF_SB + qp*256 + ((sc*2) ^ ((qp & 7) << 4)))
                        = f2bf(acc[r]);
                }
            }
        }
        __syncthreads();   // sync4

        // ---- coalesced store of this head's pre-proj slice to global ----
        #pragma unroll
        for (int i = 0; i < 2; ++i) {
            int c   = tid*2 + i;           // 0..1023
            int qp  = c >> 4;
            int s   = (c >> 2) & 3;
            int c2b = c & 3;
            s16x8 v = *(const s16x8*)(smem + OFF_SB + qp*256 +
                          (((s*64 + c2b*16)) ^ ((qp & 7) << 4)));
            int t = tok_of(qp, s);
            *(s16x8*)(preb + (size_t)t*768 + 384 + h*64 + c2b*16) = v;
        }
        // next head's staging waits on sync1; Sb reads here complete before the
        // next QK^T writes Sb (one barrier in between).
    }
}

__global__ __launch_bounds__(256, 4) void dwa_proj_kernel(
    const float* __restrict__ pw, float* __restrict__ out_g)
{
    const int tid  = threadIdx.x;
    const int lane = tid & 63;
    const int wv   = tid >> 6;
    const int g    = blockIdx.x * 4 + wv;     // 0..16383
    const int w    = g >> 4;
    const int strip = g & 15;
    const char* preb = (const char*)out_g + (size_t)w * 196608;

    const int cb = lane >> 4;
    const int arow = strip*16 + (lane & 15);

    s16x8 af[6];
    #pragma unroll
    for (int ks = 0; ks < 6; ++ks) {
        af[ks] = *(const s16x8*)(preb + (size_t)arow*768 + 384 + ks*64 + cb*16);
    }

    #pragma unroll
    for (int nt = 0; nt < 12; ++nt) {
        int orow = nt*16 + (lane & 15);
        const float* wp = pw + (size_t)orow*EMB + cb*8;
        f32x4 acc = {0.f,0.f,0.f,0.f};
        #pragma unroll
        for (int ks = 0; ks < 6; ++ks) {
            f32x4 a = *(const f32x4*)(wp + ks*32);
            f32x4 b = *(const f32x4*)(wp + ks*32 + 4);
            s16x8 bf;
            bf[0] = (short)f2bf(a[0]); bf[1] = (short)f2bf(a[1]);
            bf[2] = (short)f2bf(a[2]); bf[3] = (short)f2bf(a[3]);
            bf[4] = (short)f2bf(b[0]); bf[5] = (short)f2bf(b[1]);
            bf[6] = (short)f2bf(b[2]); bf[7] = (short)f2bf(b[3]);
            acc = mfma16(af[ks], bf, acc);
        }
        #pragma unroll
        for (int r = 0; r < 4; ++r) {
            int trow = strip*16 + (lane >> 4)*4 + r;
            out_g[(size_t)w*49152 + trow*EMB + nt*16 + (lane & 15)] = acc[r];
        }
    }
}

extern "C" void kernel_launch(void* const* d_in, const int* in_sizes, int n_in,
                              void* d_out, int out_size, void* d_ws, size_t ws_size,
                              hipStream_t stream) {
    (void)in_sizes; (void)n_in; (void)out_size; (void)d_ws; (void)ws_size;
    dwa_attn_kernel<<<dim3(NWIN), dim3(512), 0, stream>>>(
        (const float*)d_in[0],  (const float*)d_in[1],  (const float*)d_in[2],
        (const float*)d_in[3],  (const float*)d_in[4],  (const float*)d_in[5],
        (const float*)d_in[6],  (const float*)d_in[7],  (const float*)d_in[8],
        (const float*)d_in[9],  (const float*)d_in[10],
        (float*)d_out);
    dwa_proj_kernel<<<dim3(NWIN*4), dim3(256), 0, stream>>>(
        (const float*)d_in[11], (float*)d_out);
}

// Round 3
// 427.545 us; speedup vs baseline: 1.6150x; 1.6150x over previous
//
#include <hip/hip_runtime.h>

#define NWIN 1024
#define LTOK 256
#define EMB  192
#define NPAT 64
#define NHEAD 6
#define HDIM 32
#define SCALE 0.08838834764831845f
#define LN_EPS 1e-5f

typedef float f32x4 __attribute__((ext_vector_type(4)));
typedef short s16x8 __attribute__((ext_vector_type(8)));

// ---- attention kernel LDS layout (bytes) ----
#define OFF_KH  0              // [64 p][128 sc] bf16, row 256B, swz ((p&7)<<4)
#define OFF_VT  16384          // [128 sc][64 p] bf16, row 128B, swz ((sc&7)<<4)
#define OFF_PB  32768          // [64 q][64 k]  bf16, row 128B, swz ((q&7)<<4)
#define OFF_SB  40960          // [64 q] x 272B f32 (68 dwords); also phase1 partials
#define OFF_OB  58368          // [64 qp][2 hp][128 sc] bf16, row 512B, swz ((qp&7)<<4)
#define OFF_ST  91136          // stats: 6 x 64 f32
#define OFF_BH  92672          // bias_h: 225 f32 (pad 1024)
#define SMEM_BYTES 93696

__device__ __forceinline__ unsigned short f2bf(float f) {
    unsigned u = __float_as_uint(f);
    u += 0x7fffu + ((u >> 16) & 1u);
    return (unsigned short)(u >> 16);
}

__device__ __forceinline__ int tok_of(int p, int s) {
    // t = wh*32 + sh*16 + ww*2 + sw ; p = wh*8+ww, s = sh*2+sw
    return ((p >> 3) << 5) + ((s >> 1) << 4) + ((p & 7) << 1) + (s & 1);
}

__device__ __forceinline__ f32x4 mfma16(s16x8 a, s16x8 b, f32x4 c) {
    return __builtin_amdgcn_mfma_f32_16x16x32_bf16(a, b, c, 0, 0, 0);
}

__device__ __forceinline__ s16x8 ln_pack8r(const float* v, float mu, float rs,
                                           const float* __restrict__ wl,
                                           const float* __restrict__ bl,
                                           float scale) {
    f32x4 w0 = *(const f32x4*)wl;
    f32x4 w1 = *(const f32x4*)(wl + 4);
    f32x4 c0 = *(const f32x4*)bl;
    f32x4 c1 = *(const f32x4*)(bl + 4);
    s16x8 r;
    r[0] = (short)f2bf(((v[0]-mu)*rs*w0[0] + c0[0])*scale);
    r[1] = (short)f2bf(((v[1]-mu)*rs*w0[1] + c0[1])*scale);
    r[2] = (short)f2bf(((v[2]-mu)*rs*w0[2] + c0[2])*scale);
    r[3] = (short)f2bf(((v[3]-mu)*rs*w0[3] + c0[3])*scale);
    r[4] = (short)f2bf(((v[4]-mu)*rs*w1[0] + c1[0])*scale);
    r[5] = (short)f2bf(((v[5]-mu)*rs*w1[1] + c1[1])*scale);
    r[6] = (short)f2bf(((v[6]-mu)*rs*w1[2] + c1[2])*scale);
    r[7] = (short)f2bf(((v[7]-mu)*rs*w1[3] + c1[3])*scale);
    return r;
}

__device__ __forceinline__ void ln_f8r(const float* v, float mu, float rs,
                                       const float* __restrict__ wl,
                                       const float* __restrict__ bl,
                                       float* o) {
    f32x4 w0 = *(const f32x4*)wl;
    f32x4 w1 = *(const f32x4*)(wl + 4);
    f32x4 c0 = *(const f32x4*)bl;
    f32x4 c1 = *(const f32x4*)(bl + 4);
    o[0] = (v[0]-mu)*rs*w0[0] + c0[0];
    o[1] = (v[1]-mu)*rs*w0[1] + c0[1];
    o[2] = (v[2]-mu)*rs*w0[2] + c0[2];
    o[3] = (v[3]-mu)*rs*w0[3] + c0[3];
    o[4] = (v[4]-mu)*rs*w1[0] + c1[0];
    o[5] = (v[5]-mu)*rs*w1[1] + c1[1];
    o[6] = (v[6]-mu)*rs*w1[2] + c1[2];
    o[7] = (v[7]-mu)*rs*w1[3] + c1[3];
}

__device__ __forceinline__ void load_KV(const float* __restrict__ k_g,
                                        const float* __restrict__ v_g,
                                        size_t wbase, int tid, int hh,
                                        float kpre[2][8], float vpre[2][8]) {
    #pragma unroll
    for (int i = 0; i < 2; ++i) {
        int c = i*512 + tid;
        int p = c >> 4, s = (c >> 2) & 3, cb = c & 3;
        int t = tok_of(p, s);
        const float* kp = k_g + wbase + t*EMB + hh*HDIM + cb*8;
        const float* vp = v_g + wbase + t*EMB + hh*HDIM + cb*8;
        *(f32x4*)&kpre[i][0] = *(const f32x4*)kp;
        *(f32x4*)&kpre[i][4] = *(const f32x4*)(kp + 4);
        *(f32x4*)&vpre[i][0] = *(const f32x4*)vp;
        *(f32x4*)&vpre[i][4] = *(const f32x4*)(vp + 4);
    }
}

__device__ __forceinline__ void stage_K(char* smem, int tid, int hh,
                                        const float kpre[2][8], const float* stats,
                                        const float* __restrict__ lnkw,
                                        const float* __restrict__ lnkb) {
    const float* muk = stats + 128; const float* rsk = stats + 192;
    #pragma unroll
    for (int i = 0; i < 2; ++i) {
        int c = i*512 + tid;
        int p = c >> 4, s = (c >> 2) & 3, cb = c & 3;
        int chb = hh*HDIM + cb*8;
        s16x8 kk = ln_pack8r(kpre[i], muk[p], rsk[p],
                             lnkw + s*EMB + chb, lnkb + s*EMB + chb, 1.0f);
        *(s16x8*)(smem + OFF_KH + p*256 + ((s*64 + cb*16) ^ ((p & 7) << 4))) = kk;
    }
}

__device__ __forceinline__ void stage_V(char* smem, int tid, int hh,
                                        const float vpre[2][8], const float* stats,
                                        const float* __restrict__ lnvw,
                                        const float* __restrict__ lnvb) {
    const float* muv = stats + 256; const float* rsv = stats + 320;
    #pragma unroll
    for (int i = 0; i < 2; ++i) {
        int c = i*512 + tid;
        int p = c >> 4, s = (c >> 2) & 3, cb = c & 3;
        int chb = hh*HDIM + cb*8;
        float vn[8];
        ln_f8r(vpre[i], muv[p], rsv[p], lnvw + s*EMB + chb, lnvb + s*EMB + chb, vn);
        #pragma unroll
        for (int j = 0; j < 8; ++j) {
            int sc = s*32 + cb*8 + j;
            *(unsigned short*)(smem + OFF_VT + sc*128 + ((p*2) ^ ((sc & 7) << 4)))
                = f2bf(vn[j]);
        }
    }
}

__device__ __forceinline__ void load_Q(const float* __restrict__ q_g, size_t wbase,
                                       int pr, int cb, int hh, float qpre[4][8]) {
    #pragma unroll
    for (int ks = 0; ks < 4; ++ks) {
        int t = tok_of(pr, ks);
        const float* qp = q_g + wbase + t*EMB + hh*HDIM + cb*8;
        *(f32x4*)&qpre[ks][0] = *(const f32x4*)qp;
        *(f32x4*)&qpre[ks][4] = *(const f32x4*)(qp + 4);
    }
}

// Pre-projection bf16 rows live INSIDE d_out: window w, token t occupies
// bytes [w*196608 + t*768 + 384, +384). Stored as full 128B lines (head pairs).

__global__ __launch_bounds__(512, 2) void dwa_attn_kernel(
    const float* __restrict__ q_g, const float* __restrict__ k_g,
    const float* __restrict__ v_g, const float* __restrict__ mask_g,
    const float* __restrict__ lnqw, const float* __restrict__ lnqb,
    const float* __restrict__ lnkw, const float* __restrict__ lnkb,
    const float* __restrict__ lnvw, const float* __restrict__ lnvb,
    const float* __restrict__ btab, float* __restrict__ out_g)
{
    __shared__ __align__(16) char smem[SMEM_BYTES];

    const int tid  = threadIdx.x;
    const int lane = tid & 63;
    const int wv   = tid >> 6;
    const int win  = blockIdx.x;
    const size_t wbase = (size_t)win * LTOK * EMB;
    char* preb = (char*)out_g + (size_t)win * 196608;

    float* stats = (float*)(smem + OFF_ST);
    float* muq = stats;       float* rsq = stats + 64;
    float* biash = (float*)(smem + OFF_BH);

    const int mwin = win & 63;
    const float* mask_w = mask_g + (size_t)mwin * NPAT * NPAT;

    // mask is identical across heads: load once into registers (issued first)
    const int sm_qr = tid >> 3, sm_j = tid & 7;
    f32x4 mk0 = *(const f32x4*)(mask_w + sm_qr*64 + sm_j*8);
    f32x4 mk1 = *(const f32x4*)(mask_w + sm_qr*64 + sm_j*8 + 4);

    // ---------------- Phase 1: LN stats for q,k,v (single pass) ----------------
    {
        float* part = (float*)(smem + OFF_SB);   // [256 t][2 half][6]
        const int t = tid >> 1, half = tid & 1;
        const f32x4* qp = (const f32x4*)(q_g + wbase + t*EMB + half*96);
        const f32x4* kp = (const f32x4*)(k_g + wbase + t*EMB + half*96);
        const f32x4* vp = (const f32x4*)(v_g + wbase + t*EMB + half*96);
        float s1q=0.f,s2q=0.f,s1k=0.f,s2k=0.f,s1v=0.f,s2v=0.f;
        #pragma unroll 4
        for (int i = 0; i < 24; ++i) {
            f32x4 a = qp[i];
            s1q += a[0]+a[1]+a[2]+a[3];
            s2q += a[0]*a[0]+a[1]*a[1]+a[2]*a[2]+a[3]*a[3];
            f32x4 b = kp[i];
            s1k += b[0]+b[1]+b[2]+b[3];
            s2k += b[0]*b[0]+b[1]*b[1]+b[2]*b[2]+b[3]*b[3];
            f32x4 c = vp[i];
            s1v += c[0]+c[1]+c[2]+c[3];
            s2v += c[0]*c[0]+c[1]*c[1]+c[2]*c[2]+c[3]*c[3];
        }
        float* pp = part + (t*2 + half)*6;
        pp[0]=s1q; pp[1]=s2q; pp[2]=s1k; pp[3]=s2k; pp[4]=s1v; pp[5]=s2v;
        __syncthreads();
        if (tid < NPAT) {
            float S[6] = {0.f,0.f,0.f,0.f,0.f,0.f};
            #pragma unroll
            for (int s = 0; s < 4; ++s) {
                int tt = tok_of(tid, s);
                const float* pr_ = part + tt*12;
                #pragma unroll
                for (int x = 0; x < 6; ++x) S[x] += pr_[x] + pr_[6 + x];
            }
            #pragma unroll
            for (int x = 0; x < 3; ++x) {
                float mu  = S[2*x] * (1.f/768.f);
                float var = S[2*x+1] * (1.f/768.f) - mu*mu;
                stats[x*128 + tid]      = mu;
                stats[x*128 + 64 + tid] = rsqrtf(var + LN_EPS);
            }
        }
        __syncthreads();
    }

    const int mstrip = wv >> 1;
    const int pr = mstrip*16 + (lane & 15);
    const int cb = lane >> 4;

    // ---------------- Prologue: stage K/V/bias/Q for head 0 ----------------
    float qpre[4][8];
    {
        float kpre[2][8], vpre[2][8];
        load_KV(k_g, v_g, wbase, tid, 0, kpre, vpre);
        load_Q(q_g, wbase, pr, cb, 0, qpre);
        if (tid < 225) biash[tid] = btab[tid * NHEAD];
        stage_K(smem, tid, 0, kpre, stats, lnkw, lnkb);
        stage_V(smem, tid, 0, vpre, stats, lnvw, lnvb);
    }
    __syncthreads();

    // ---------------- Head loop ----------------
    for (int h = 0; h < NHEAD; ++h) {
        // step1: issue K/V (+bias) prefetch for h+1
        float kpre[2][8], vpre[2][8]; float breg = 0.f;
        if (h < NHEAD-1) {
            load_KV(k_g, v_g, wbase, tid, h+1, kpre, vpre);
            if (tid < 225) breg = btab[tid * NHEAD + h + 1];
        }

        // step2: QK^T from qpre regs + KH LDS -> S
        {
            int nhalf = wv & 1;
            float mu = muq[pr], rs = rsq[pr];
            f32x4 acc0 = {0.f,0.f,0.f,0.f};
            f32x4 acc1 = {0.f,0.f,0.f,0.f};
            #pragma unroll
            for (int ks = 0; ks < 4; ++ks) {
                int chb = h*HDIM + cb*8;
                s16x8 af = ln_pack8r(qpre[ks], mu, rs,
                                     lnqw + ks*EMB + chb, lnqb + ks*EMB + chb, SCALE);
                {
                    int row = (nhalf*2 + 0)*16 + (lane & 15);
                    s16x8 bf = *(const s16x8*)(smem + OFF_KH + row*256 +
                                  ((ks*64 + cb*16) ^ ((row & 7) << 4)));
                    acc0 = mfma16(af, bf, acc0);
                }
                {
                    int row = (nhalf*2 + 1)*16 + (lane & 15);
                    s16x8 bf = *(const s16x8*)(smem + OFF_KH + row*256 +
                                  ((ks*64 + cb*16) ^ ((row & 7) << 4)));
                    acc1 = mfma16(af, bf, acc1);
                }
            }
            float* Sb = (float*)(smem + OFF_SB);
            #pragma unroll
            for (int r = 0; r < 4; ++r) {
                int qr = mstrip*16 + (lane >> 4)*4 + r;
                Sb[qr*68 + (nhalf*2+0)*16 + (lane & 15)] = acc0[r];
                Sb[qr*68 + (nhalf*2+1)*16 + (lane & 15)] = acc1[r];
            }
        }
        __syncthreads();   // sync2: S ready, KH free, qpre consumed

        // step3: softmax (+bias +mask-regs) : 8 threads per row
        {
            const float* Sb = (const float*)(smem + OFF_SB);
            f32x4 s0 = *(const f32x4*)(Sb + sm_qr*68 + sm_j*8);
            f32x4 s1 = *(const f32x4*)(Sb + sm_qr*68 + sm_j*8 + 4);
            int qh = sm_qr >> 3, qw = sm_qr & 7;
            float vals[8];
            #pragma unroll
            for (int jj = 0; jj < 8; ++jj) {
                int kc = sm_j*8 + jj;
                int idx = (qh - (kc >> 3) + 7)*15 + (qw - (kc & 7) + 7);
                vals[jj] = (jj < 4 ? s0[jj] : s1[jj-4]) +
                           (jj < 4 ? mk0[jj] : mk1[jj-4]) + biash[idx];
            }
            float mx = vals[0];
            #pragma unroll
            for (int jj = 1; jj < 8; ++jj) mx = fmaxf(mx, vals[jj]);
            mx = fmaxf(mx, __shfl_xor(mx, 1));
            mx = fmaxf(mx, __shfl_xor(mx, 2));
            mx = fmaxf(mx, __shfl_xor(mx, 4));
            float sum = 0.f;
            #pragma unroll
            for (int jj = 0; jj < 8; ++jj) { vals[jj] = __expf(vals[jj] - mx); sum += vals[jj]; }
            sum += __shfl_xor(sum, 1);
            sum += __shfl_xor(sum, 2);
            sum += __shfl_xor(sum, 4);
            float rinv = 1.f / sum;
            s16x8 pv;
            #pragma unroll
            for (int jj = 0; jj < 8; ++jj) pv[jj] = (short)f2bf(vals[jj] * rinv);
            *(s16x8*)(smem + OFF_PB + sm_qr*128 + ((sm_j*16) ^ ((sm_qr & 7) << 4))) = pv;
        }
        // step3b: write KH for h+1 (KH free after sync2); re-issue Q prefetch
        if (h < NHEAD-1) {
            stage_K(smem, tid, h+1, kpre, stats, lnkw, lnkb);
            load_Q(q_g, wbase, pr, cb, h+1, qpre);
        }
        __syncthreads();   // sync3: P ready (KH writes also done)

        // step5: P @ V -> OB side (h&1)
        {
            int m = wv >> 1, nset = wv & 1;
            int prow = m*16 + (lane & 15);
            s16x8 ap0 = *(const s16x8*)(smem + OFF_PB + prow*128 +
                          ((0*64 + cb*16) ^ ((prow & 7) << 4)));
            s16x8 ap1 = *(const s16x8*)(smem + OFF_PB + prow*128 +
                          ((1*64 + cb*16) ^ ((prow & 7) << 4)));
            #pragma unroll
            for (int i = 0; i < 4; ++i) {
                int nt = nset*4 + i;
                int brow = nt*16 + (lane & 15);     // sc
                f32x4 acc = {0.f,0.f,0.f,0.f};
                s16x8 bf0 = *(const s16x8*)(smem + OFF_VT + brow*128 +
                              ((0*64 + cb*16) ^ ((brow & 7) << 4)));
                s16x8 bf1 = *(const s16x8*)(smem + OFF_VT + brow*128 +
                              ((1*64 + cb*16) ^ ((brow & 7) << 4)));
                acc = mfma16(ap0, bf0, acc);
                acc = mfma16(ap1, bf1, acc);
                int sc = nt*16 + (lane & 15);
                #pragma unroll
                for (int r = 0; r < 4; ++r) {
                    int qp = m*16 + (lane >> 4)*4 + r;
                    *(unsigned short*)(smem + OFF_OB + qp*512 +
                        (((h & 1)*256 + sc*2) ^ ((qp & 7) << 4))) = f2bf(acc[r]);
                }
            }
        }
        __syncthreads();   // sync4: OB ready; VT free

        // step6: every 2nd head, store full 128B/token head-pair lines
        if (h & 1) {
            int hpair = h >> 1;
            #pragma unroll
            for (int i = 0; i < 4; ++i) {
                int c = i*512 + tid;             // 2048 chunks of 16B
                int t = c >> 3, ch8 = c & 7;
                int hp = ch8 >> 2, c2b = ch8 & 3;
                int qp = ((t >> 5) << 3) | ((t >> 1) & 7);
                int s  = (((t >> 4) & 1) << 1) | (t & 1);
                s16x8 v = *(const s16x8*)(smem + OFF_OB + qp*512 +
                              ((hp*256 + s*64 + c2b*16) ^ ((qp & 7) << 4)));
                *(s16x8*)(preb + (size_t)t*768 + 384 + hpair*128 + hp*64 + c2b*16) = v;
            }
        }
        // step7: write VT + bias for h+1
        if (h < NHEAD-1) {
            stage_V(smem, tid, h+1, vpre, stats, lnvw, lnvb);
            if (tid < 225) biash[tid] = breg;
        }
        __syncthreads();   // sync5: VT/bias ready; OB free for next pair
    }
}

// ---- projection: 1 block per window, W staged bf16 in LDS once ----
__global__ __launch_bounds__(256, 2) void dwa_proj_kernel(
    const float* __restrict__ pw, float* __restrict__ out_g)
{
    __shared__ __align__(16) char smem[73728];   // [192 orow][192 ch] bf16, swz

    const int tid  = threadIdx.x;
    const int lane = tid & 63;
    const int wv   = tid >> 6;
    const int w    = blockIdx.x;
    const char* preb = (const char*)out_g + (size_t)w * 196608;
    const int cb = lane >> 4;

    // preload all A fragments (issued before staging; overlaps W stage + barrier)
    s16x8 af[4][6];
    #pragma unroll
    for (int si = 0; si < 4; ++si) {
        int strip = wv*4 + si;
        int arow = strip*16 + (lane & 15);
        #pragma unroll
        for (int ks = 0; ks < 6; ++ks)
            af[si][ks] = *(const s16x8*)(preb + (size_t)arow*768 + 384 + ks*64 + cb*16);
    }

    // stage W (192x192 f32 -> bf16), 4608 chunks of 8
    #pragma unroll 2
    for (int i = 0; i < 18; ++i) {
        int c = i*256 + tid;
        int orow = c / 24, cb8 = c % 24;
        const float* wp = pw + (size_t)orow*EMB + cb8*8;
        f32x4 a = *(const f32x4*)wp;
        f32x4 b = *(const f32x4*)(wp + 4);
        s16x8 w8;
        w8[0] = (short)f2bf(a[0]); w8[1] = (short)f2bf(a[1]);
        w8[2] = (short)f2bf(a[2]); w8[3] = (short)f2bf(a[3]);
        w8[4] = (short)f2bf(b[0]); w8[5] = (short)f2bf(b[1]);
        w8[6] = (short)f2bf(b[2]); w8[7] = (short)f2bf(b[3]);
        *(s16x8*)(smem + orow*384 + ((cb8*16) ^ ((orow & 7) << 4))) = w8;
    }
    __syncthreads();

    #pragma unroll
    for (int si = 0; si < 4; ++si) {
        int strip = wv*4 + si;
        #pragma unroll
        for (int nt = 0; nt < 12; ++nt) {
            int orow = nt*16 + (lane & 15);
            f32x4 acc = {0.f,0.f,0.f,0.f};
            #pragma unroll
            for (int ks = 0; ks < 6; ++ks) {
                s16x8 bf = *(const s16x8*)(smem + orow*384 +
                              ((ks*64 + cb*16) ^ ((orow & 7) << 4)));
                acc = mfma16(af[si][ks], bf, acc);
            }
            #pragma unroll
            for (int r = 0; r < 4; ++r) {
                int trow = strip*16 + (lane >> 4)*4 + r;
                out_g[(size_t)w*49152 + trow*EMB + nt*16 + (lane & 15)] = acc[r];
            }
        }
    }
}

extern "C" void kernel_launch(void* const* d_in, const int* in_sizes, int n_in,
                              void* d_out, int out_size, void* d_ws, size_t ws_size,
                              hipStream_t stream) {
    (void)in_sizes; (void)n_in; (void)out_size; (void)d_ws; (void)ws_size;
    dwa_attn_kernel<<<dim3(NWIN), dim3(512), 0, stream>>>(
        (const float*)d_in[0],  (const float*)d_in[1],  (const float*)d_in[2],
        (const float*)d_in[3],  (const float*)d_in[4],  (const float*)d_in[5],
        (const float*)d_in[6],  (const float*)d_in[7],  (const float*)d_in[8],
        (const float*)d_in[9],  (const float*)d_in[10],
        (float*)d_out);
    dwa_proj_kernel<<<dim3(NWIN), dim3(256), 0, stream>>>(
        (const float*)d_in[11], (float*)d_out);
}